// Round 1
// baseline (42.681 us; speedup 1.0000x reference)
//
#include <hip/hip_runtime.h>

#define NCH 14

// Per-row loss: xs/ts are compile-time-indexable register arrays (fully
// unrolled, constant indices -> stays in VGPRs, no scratch).
__device__ __forceinline__ float row_loss(const float* xs, const float* ts, unsigned pack) {
    // gb bit g set iff any target in group g is > 0
    unsigned gb = 0u;
#pragma unroll
    for (int c = 0; c < NCH; ++c) {
        int gc = (pack >> (2 * c)) & 3;
        gb |= (ts[c] > 0.0f) ? (1u << gc) : 0u;
    }
    float acc = 0.0f;
#pragma unroll
    for (int c = 0; c < NCH; ++c) {
        int gc = (pack >> (2 * c)) & 3;
        float xv = xs[c], tv = ts[c];
        float bce = fmaxf(xv, 0.0f) - xv * tv + __logf(1.0f + __expf(-fabsf(xv)));
        bool keep = (gc == 0) || ((gb >> gc) & 1u);
        acc += keep ? bce : 0.0f;
    }
    return acc;
}

__global__ __launch_bounds__(256) void bce_partial(
    const float* __restrict__ x, const float* __restrict__ t,
    const int* __restrict__ groups, float* __restrict__ partial, int rows)
{
    // Pack the 14 2-bit group ids into one register (wave-uniform value).
    unsigned pack = 0u;
#pragma unroll
    for (int c = 0; c < NCH; ++c) pack |= ((unsigned)(groups[c] & 3)) << (2 * c);

    const int pairs = rows >> 1;
    const int gtid = blockIdx.x * blockDim.x + threadIdx.x;
    const int nthreads = gridDim.x * blockDim.x;

    float acc = 0.0f;

    for (int p = gtid; p < pairs; p += nthreads) {
        const float4* xp = (const float4*)(x + (size_t)p * (2 * NCH));
        const float4* tp = (const float4*)(t + (size_t)p * (2 * NCH));
        float xs[2 * NCH], ts[2 * NCH];
#pragma unroll
        for (int j = 0; j < 7; ++j) {
            float4 xv = xp[j];
            float4 tv = tp[j];
            xs[4 * j + 0] = xv.x; xs[4 * j + 1] = xv.y; xs[4 * j + 2] = xv.z; xs[4 * j + 3] = xv.w;
            ts[4 * j + 0] = tv.x; ts[4 * j + 1] = tv.y; ts[4 * j + 2] = tv.z; ts[4 * j + 3] = tv.w;
        }
        acc += row_loss(xs, ts, pack);
        acc += row_loss(xs + NCH, ts + NCH, pack);
    }

    // Odd-row tail (not hit for B=2e6, kept for generality).
    if ((rows & 1) && gtid == 0) {
        const size_t base = (size_t)(rows - 1) * NCH;
        float xs[NCH], ts[NCH];
#pragma unroll
        for (int c = 0; c < NCH; ++c) { xs[c] = x[base + c]; ts[c] = t[base + c]; }
        acc += row_loss(xs, ts, pack);
    }

    // Wave (64-lane) reduction.
#pragma unroll
    for (int off = 32; off > 0; off >>= 1) acc += __shfl_xor(acc, off);

    __shared__ float wsum[4];  // 256 threads = 4 waves
    const int lane = threadIdx.x & 63;
    const int wid = threadIdx.x >> 6;
    if (lane == 0) wsum[wid] = acc;
    __syncthreads();
    if (threadIdx.x == 0)
        partial[blockIdx.x] = wsum[0] + wsum[1] + wsum[2] + wsum[3];
}

__global__ __launch_bounds__(256) void finalize(
    const float* __restrict__ partial, int n, float* __restrict__ out, double inv_count)
{
    double s = 0.0;
    for (int i = threadIdx.x; i < n; i += 256) s += (double)partial[i];

    __shared__ double sd[256];
    sd[threadIdx.x] = s;
    __syncthreads();
#pragma unroll
    for (int step = 128; step > 0; step >>= 1) {
        if (threadIdx.x < step) sd[threadIdx.x] += sd[threadIdx.x + step];
        __syncthreads();
    }
    if (threadIdx.x == 0) out[0] = (float)(sd[0] * inv_count);
}

extern "C" void kernel_launch(void* const* d_in, const int* in_sizes, int n_in,
                              void* d_out, int out_size, void* d_ws, size_t ws_size,
                              hipStream_t stream) {
    const float* x = (const float*)d_in[0];
    const float* t = (const float*)d_in[1];
    const int* groups = (const int*)d_in[2];
    float* out = (float*)d_out;
    float* partial = (float*)d_ws;

    const int total = in_sizes[0];
    const int rows = total / NCH;

    int blocks = 2048;
    if ((size_t)blocks * sizeof(float) > ws_size)
        blocks = (int)(ws_size / sizeof(float));
    if (blocks < 1) blocks = 1;

    bce_partial<<<blocks, 256, 0, stream>>>(x, t, groups, partial, rows);

    const double inv_count = 1.0 / ((double)rows * (double)NCH);
    finalize<<<1, 256, 0, stream>>>(partial, blocks, out, inv_count);
}